// Round 1
// baseline (8693.111 us; speedup 1.0000x reference)
//
#include <hip/hip_runtime.h>
#include <hip/hip_bf16.h>
#include <math.h>

#define NN 16384
#define NG 512
#define NE2 65536
#define NE3 393216
#define DEMB 300
#define DSCH 128
#define NRBF 50

__device__ __forceinline__ float sspf(float x) {
  // shifted softplus: log(1+e^x) - log(2), numerically stable
  float sp = log1pf(expf(-fabsf(x))) + fmaxf(x, 0.f);
  return sp - 0.69314718055994530942f;
}

// ---------------- small elementwise / scatter kernels ----------------

__global__ void k_counts(const int* __restrict__ batch, float* __restrict__ counts) {
  int i = blockIdx.x * blockDim.x + threadIdx.x;
  if (i < NN) atomicAdd(&counts[batch[i]], 1.0f);
}

__global__ void k_hinit(const int* __restrict__ x2d, const float* __restrict__ e1,
                        const float* __restrict__ e2, float* __restrict__ h) {
  int i = blockIdx.x * blockDim.x + threadIdx.x;
  if (i >= NN * DEMB) return;
  int n = i / DEMB, c = i - n * DEMB;
  h[i] = e1[x2d[2 * n] * DEMB + c] + e2[x2d[2 * n + 1] * DEMB + c];
}

__global__ void k_vninit(const float* __restrict__ vni, float* __restrict__ vn) {
  int i = blockIdx.x * blockDim.x + threadIdx.x;
  if (i >= NG * DEMB) return;
  vn[i] = vni[i % DEMB];
}

__global__ void k_addvn(float* __restrict__ h, const float* __restrict__ vn,
                        const int* __restrict__ batch) {
  int i = blockIdx.x * blockDim.x + threadIdx.x;
  if (i >= NN * DEMB) return;
  int n = i / DEMB, c = i - n * DEMB;
  h[i] += vn[batch[n] * DEMB + c];
}

__global__ void k_gin_edge(const float* __restrict__ h, const int* __restrict__ ei2,
                           const int* __restrict__ ea2, const float* __restrict__ bond1,
                           const float* __restrict__ bond2, float* __restrict__ agg) {
  int i = blockIdx.x * blockDim.x + threadIdx.x;  // e*75 + c4
  if (i >= NE2 * 75) return;
  int e = i / 75, c = i - e * 75;
  int s = ei2[e], d = ei2[NE2 + e];
  int a0 = ea2[2 * e], a1 = ea2[2 * e + 1];
  const float4 hv = *(const float4*)(h + (size_t)s * DEMB + c * 4);
  const float4 b1 = *(const float4*)(bond1 + (size_t)a0 * DEMB + c * 4);
  const float4 b2 = *(const float4*)(bond2 + (size_t)a1 * DEMB + c * 4);
  float4 m;
  m.x = fmaxf(hv.x + b1.x + b2.x, 0.f);
  m.y = fmaxf(hv.y + b1.y + b2.y, 0.f);
  m.z = fmaxf(hv.z + b1.z + b2.z, 0.f);
  m.w = fmaxf(hv.w + b1.w + b2.w, 0.f);
  float* dp = agg + (size_t)d * DEMB + c * 4;
  atomicAdd(dp + 0, m.x);
  atomicAdd(dp + 1, m.y);
  atomicAdd(dp + 2, m.z);
  atomicAdd(dp + 3, m.w);
}

__global__ void k_segsum(const float* __restrict__ x, const int* __restrict__ batch,
                         float* __restrict__ out, int n, int W) {
  int i = blockIdx.x * blockDim.x + threadIdx.x;
  if (i >= n * W) return;
  int r = i / W, c = i - r * W;
  atomicAdd(&out[batch[r] * W + c], x[i]);
}

__global__ void k_div(float* __restrict__ buf, const float* __restrict__ counts, int B, int W) {
  int i = blockIdx.x * blockDim.x + threadIdx.x;
  if (i >= B * W) return;
  buf[i] /= fmaxf(counts[i / W], 1.0f);
}

__global__ void k_rbf(const int* __restrict__ ei3, const float* __restrict__ pos,
                      float* __restrict__ rbf, float* __restrict__ C3) {
  int i = blockIdx.x * blockDim.x + threadIdx.x;
  if (i >= NE3 * NRBF) return;
  int e = i / NRBF, k = i - e * NRBF;
  int s = ei3[e], d = ei3[NE3 + e];
  float dx = pos[3 * d] - pos[3 * s];
  float dy = pos[3 * d + 1] - pos[3 * s + 1];
  float dz = pos[3 * d + 2] - pos[3 * s + 2];
  float dist = sqrtf(dx * dx + dy * dy + dz * dz);
  const float step = 10.0f / 49.0f;
  const float coeff = -0.5f / (step * step);
  float t = dist - (float)k * step;
  rbf[i] = expf(coeff * t * t);
  if (k == 0) C3[e] = 0.5f * (cosf(dist * (3.14159265358979323846f / 10.0f)) + 1.0f);
}

__global__ void k_hsinit(const int* __restrict__ z, const float* __restrict__ emb,
                         float* __restrict__ hs) {
  int i = blockIdx.x * blockDim.x + threadIdx.x;
  if (i >= NN * DSCH) return;
  hs[i] = emb[z[i >> 7] * DSCH + (i & 127)];
}

__global__ void k_gate(const float* __restrict__ gh, const float* __restrict__ gW2,
                       const float* __restrict__ gb2, float* __restrict__ g) {
  int m = blockIdx.x * blockDim.x + threadIdx.x;
  if (m >= NG) return;
  float acc = gb2[0];
  for (int k = 0; k < 128; ++k) acc += gh[m * 128 + k] * gW2[k];
  g[m] = 1.0f / (1.0f + expf(-acc));
}

__global__ void k_hf(const float* __restrict__ g, const float* __restrict__ hcat,
                     float* __restrict__ hf) {
  int i = blockIdx.x * blockDim.x + threadIdx.x;
  if (i >= NG * DEMB) return;
  int m = i / DEMB, c = i - m * DEMB;
  float gg = g[m];
  hf[i] = gg * hcat[m * 600 + c] + (1.0f - gg) * hcat[m * 600 + 300 + c];
}

// ---------------- generic fp32 GEMM: C = act((A[+A2]) @ B + bias) [*gamma+beta] [+Cin] ----------------
// A:[M,K] row-major, B:[K,N] row-major, C:[M,ldc]

template <int ACT>  // 0 none, 1 relu, 2 ssp
__global__ __launch_bounds__(256) void k_gemm(
    const float* __restrict__ A, const float* __restrict__ A2, const float* __restrict__ B,
    const float* __restrict__ bias, const float* __restrict__ scale,
    const float* __restrict__ shift, const float* __restrict__ Cin, float* __restrict__ Cout,
    int M, int N, int K, int ldc) {
  __shared__ float sA[16][65];
  __shared__ float sB[16][64];
  int tid = threadIdx.x;
  int tx = tid & 15, ty = tid >> 4;
  int bm = blockIdx.y * 64, bn = blockIdx.x * 64;
  float acc[4][4] = {};
  for (int k0 = 0; k0 < K; k0 += 16) {
#pragma unroll
    for (int t = 0; t < 4; ++t) {
      int i = tid + t * 256;
      int m = i >> 4, kk = i & 15;
      int gm = bm + m, gk = k0 + kk;
      float v = 0.f;
      if (gm < M && gk < K) {
        v = A[(size_t)gm * K + gk];
        if (A2) v += A2[(size_t)gm * K + gk];
      }
      sA[kk][m] = v;
    }
#pragma unroll
    for (int t = 0; t < 4; ++t) {
      int i = tid + t * 256;
      int kk = i >> 6, n = i & 63;
      int gk = k0 + kk, gn = bn + n;
      sB[kk][n] = (gk < K && gn < N) ? B[(size_t)gk * N + gn] : 0.f;
    }
    __syncthreads();
#pragma unroll
    for (int kk = 0; kk < 16; ++kk) {
      float a[4], b[4];
#pragma unroll
      for (int i = 0; i < 4; ++i) a[i] = sA[kk][ty + 16 * i];
#pragma unroll
      for (int j = 0; j < 4; ++j) b[j] = sB[kk][tx + 16 * j];
#pragma unroll
      for (int i = 0; i < 4; ++i)
#pragma unroll
        for (int j = 0; j < 4; ++j) acc[i][j] = fmaf(a[i], b[j], acc[i][j]);
    }
    __syncthreads();
  }
#pragma unroll
  for (int i = 0; i < 4; ++i) {
    int gm = bm + ty + 16 * i;
    if (gm >= M) continue;
#pragma unroll
    for (int j = 0; j < 4; ++j) {
      int gn = bn + tx + 16 * j;
      if (gn >= N) continue;
      float v = acc[i][j];
      if (bias) v += bias[gn];
      if (scale) v = v * scale[gn] + shift[gn];
      if (ACT == 1) v = fmaxf(v, 0.f);
      if (ACT == 2) v = sspf(v);
      if (Cin) v += Cin[(size_t)gm * ldc + gn];
      Cout[(size_t)gm * ldc + gn] = v;
    }
  }
}

// ---------------- fused SchNet filter-net + CFConv scatter ----------------
// per block: 32 edges. t1 = ssp(rbf@mW1+mb1); Wf = (t1@mW2+mb2)*C; atomicAdd agg3[dst] += x1[src]*Wf

__global__ __launch_bounds__(256) void k_filter_conv(
    const float* __restrict__ rbf, const float* __restrict__ C3, const float* __restrict__ x1,
    const int* __restrict__ src3, const int* __restrict__ dst3, const float* __restrict__ mW1,
    const float* __restrict__ mb1, const float* __restrict__ mW2, const float* __restrict__ mb2,
    float* __restrict__ agg3) {
  __shared__ float s_rbf[32][52];
  __shared__ float s_t1[32][132];
  __shared__ float s_B[32][128];
  int e0 = blockIdx.x * 32;
  int tid = threadIdx.x;
  int tx = tid & 15, ty = tid >> 4;
  for (int i = tid; i < 32 * NRBF; i += 256) {
    int e = i / NRBF, k = i - (i / NRBF) * NRBF;
    s_rbf[e][k] = rbf[(size_t)(e0 + e) * NRBF + k];
  }
  // stage 1: K=50
  float acc[2][8] = {};
  for (int k0 = 0; k0 < NRBF; k0 += 32) {
    int kc = (NRBF - k0) < 32 ? (NRBF - k0) : 32;
    __syncthreads();
    for (int i = tid; i < 32 * 128; i += 256) {
      int kk = i >> 7, j = i & 127;
      s_B[kk][j] = (kk < kc) ? mW1[(k0 + kk) * 128 + j] : 0.f;
    }
    __syncthreads();
    for (int kk = 0; kk < kc; ++kk) {
      float b[8];
#pragma unroll
      for (int j = 0; j < 8; ++j) b[j] = s_B[kk][tx + 16 * j];
#pragma unroll
      for (int i = 0; i < 2; ++i) {
        float a = s_rbf[ty + 16 * i][k0 + kk];
#pragma unroll
        for (int j = 0; j < 8; ++j) acc[i][j] = fmaf(a, b[j], acc[i][j]);
      }
    }
  }
#pragma unroll
  for (int i = 0; i < 2; ++i)
#pragma unroll
    for (int j = 0; j < 8; ++j) s_t1[ty + 16 * i][tx + 16 * j] = sspf(acc[i][j] + mb1[tx + 16 * j]);
  // stage 2: K=128
  float acc2[2][8] = {};
  for (int k0 = 0; k0 < 128; k0 += 32) {
    __syncthreads();
    for (int i = tid; i < 32 * 128; i += 256) {
      int kk = i >> 7, j = i & 127;
      s_B[kk][j] = mW2[(k0 + kk) * 128 + j];
    }
    __syncthreads();
    for (int kk = 0; kk < 32; ++kk) {
      float b[8];
#pragma unroll
      for (int j = 0; j < 8; ++j) b[j] = s_B[kk][tx + 16 * j];
#pragma unroll
      for (int i = 0; i < 2; ++i) {
        float a = s_t1[ty + 16 * i][k0 + kk];
#pragma unroll
        for (int j = 0; j < 8; ++j) acc2[i][j] = fmaf(a, b[j], acc2[i][j]);
      }
    }
  }
#pragma unroll
  for (int i = 0; i < 2; ++i) {
    int e = e0 + ty + 16 * i;
    int s = src3[e], d = dst3[e];
    float c = C3[e];
#pragma unroll
    for (int j = 0; j < 8; ++j) {
      int col = tx + 16 * j;
      float wf = (acc2[i][j] + mb2[col]) * c;
      atomicAdd(&agg3[(size_t)d * 128 + col], wf * x1[(size_t)s * 128 + col]);
    }
  }
}

// ---------------- host ----------------

static inline void run_gemm(hipStream_t st, const float* A, const float* A2, const float* B,
                            const float* bias, const float* scale, const float* shift,
                            const float* Cin, float* Cout, int M, int N, int K, int ldc, int act) {
  dim3 grid((N + 63) / 64, (M + 63) / 64);
  if (act == 0)
    k_gemm<0><<<grid, 256, 0, st>>>(A, A2, B, bias, scale, shift, Cin, Cout, M, N, K, ldc);
  else if (act == 1)
    k_gemm<1><<<grid, 256, 0, st>>>(A, A2, B, bias, scale, shift, Cin, Cout, M, N, K, ldc);
  else
    k_gemm<2><<<grid, 256, 0, st>>>(A, A2, B, bias, scale, shift, Cin, Cout, M, N, K, ldc);
}

extern "C" void kernel_launch(void* const* d_in, const int* in_sizes, int n_in, void* d_out,
                              int out_size, void* d_ws, size_t ws_size, hipStream_t stream) {
  const int* x2d = (const int*)d_in[0];
  const int* ei2 = (const int*)d_in[1];
  const int* ea2 = (const int*)d_in[2];
  const int* batch = (const int*)d_in[3];
  const int* z = (const int*)d_in[4];
  const float* pos = (const float*)d_in[5];
  const int* ei3 = (const int*)d_in[6];
  const float* atom_emb1 = (const float*)d_in[7];
  const float* atom_emb2 = (const float*)d_in[8];
  const float* vn_init = (const float*)d_in[9];
  const float* gin_W1 = (const float*)d_in[10];
  const float* gin_b1 = (const float*)d_in[11];
  const float* gin_W2 = (const float*)d_in[12];
  const float* gin_b2 = (const float*)d_in[13];
  const float* gin_bond1 = (const float*)d_in[14];
  const float* gin_bond2 = (const float*)d_in[15];
  const float* gin_gamma = (const float*)d_in[16];
  const float* gin_beta = (const float*)d_in[17];
  const float* vn_W1 = (const float*)d_in[18];
  const float* vn_b1 = (const float*)d_in[19];
  const float* vn_W2 = (const float*)d_in[20];
  const float* vn_b2 = (const float*)d_in[21];
  const float* sch_emb = (const float*)d_in[22];
  const float* s_mW1 = (const float*)d_in[23];
  const float* s_mb1 = (const float*)d_in[24];
  const float* s_mW2 = (const float*)d_in[25];
  const float* s_mb2 = (const float*)d_in[26];
  const float* s_lin1W = (const float*)d_in[27];
  const float* s_lin2W = (const float*)d_in[28];
  const float* s_lin2b = (const float*)d_in[29];
  const float* s_linW = (const float*)d_in[30];
  const float* s_linb = (const float*)d_in[31];
  const float* p2W = (const float*)d_in[32];
  const float* p2b = (const float*)d_in[33];
  const float* p3W = (const float*)d_in[34];
  const float* p3b = (const float*)d_in[35];
  const float* gW1 = (const float*)d_in[36];
  const float* gb1 = (const float*)d_in[37];
  const float* gW2 = (const float*)d_in[38];
  const float* gb2 = (const float*)d_in[39];
  const float* cW1 = (const float*)d_in[40];
  const float* cb1 = (const float*)d_in[41];
  const float* cW2 = (const float*)d_in[42];
  const float* cb2 = (const float*)d_in[43];

  float* ws = (float*)d_ws;
  float* h = ws;                    // 16384*300
  float* agg = ws + 4915200;        // 16384*300
  float* y1 = ws + 9830400;         // 16384*600
  float* rbf = ws;                  // SchNet phase alias: 393216*50 == 19660800
  float* C3 = ws + 19660800;        // 393216
  float* hs = ws + 20054016;        // 16384*128
  float* x1 = ws + 22151168;        // 16384*128
  float* agg3 = ws + 24248320;      // 16384*128
  float* sx2 = ws + 26345472;       // 16384*128
  float* counts = ws + 28442624;    // 512
  float* vn = ws + 28443136;        // 512*300
  float* vnsum = ws + 28596736;     // 512*300
  float* vnh = ws + 28750336;       // 512*600
  float* h2d = ws + 29057536;       // 512*300
  float* h3d = ws + 29211136;       // 512*128
  float* hcat = ws + 29276672;      // 512*600  (h2p | h3p)
  float* gh = ws + 29583872;        // 512*128
  float* gbuf = ws + 29649408;      // 512
  float* hf = ws + 29649920;        // 512*300
  float* c1 = ws + 29803520;        // 512*150  -> end 29880320 floats (~120 MB)

  // counts
  hipMemsetAsync(counts, 0, 512 * sizeof(float), stream);
  k_counts<<<(NN + 255) / 256, 256, 0, stream>>>(batch, counts);

  // ---- GIN ----
  k_hinit<<<(NN * DEMB + 255) / 256, 256, 0, stream>>>(x2d, atom_emb1, atom_emb2, h);
  k_vninit<<<(NG * DEMB + 255) / 256, 256, 0, stream>>>(vn_init, vn);
  for (int l = 0; l < 5; ++l) {
    k_addvn<<<(NN * DEMB + 255) / 256, 256, 0, stream>>>(h, vn, batch);
    hipMemsetAsync(agg, 0, (size_t)NN * DEMB * sizeof(float), stream);
    k_gin_edge<<<(NE2 * 75 + 255) / 256, 256, 0, stream>>>(
        h, ei2, ea2, gin_bond1 + l * 6 * DEMB, gin_bond2 + l * 3 * DEMB, agg);
    run_gemm(stream, h, agg, gin_W1 + (size_t)l * 180000, gin_b1 + l * 600, nullptr, nullptr,
             nullptr, y1, NN, 600, 300, 600, 1);
    run_gemm(stream, y1, nullptr, gin_W2 + (size_t)l * 180000, gin_b2 + l * 300,
             gin_gamma + l * 300, gin_beta + l * 300, nullptr, h, NN, 300, 600, 300,
             (l < 4) ? 1 : 0);
    if (l < 4) {
      hipMemsetAsync(vnsum, 0, (size_t)NG * DEMB * sizeof(float), stream);
      k_segsum<<<(NN * DEMB + 255) / 256, 256, 0, stream>>>(h, batch, vnsum, NN, DEMB);
      run_gemm(stream, vnsum, vn, vn_W1 + (size_t)l * 180000, vn_b1 + l * 600, nullptr, nullptr,
               nullptr, vnh, NG, 600, 300, 600, 1);
      run_gemm(stream, vnh, nullptr, vn_W2 + (size_t)l * 180000, vn_b2 + l * 300, nullptr, nullptr,
               nullptr, vn, NG, 300, 600, 300, 1);
    }
  }
  hipMemsetAsync(h2d, 0, (size_t)NG * DEMB * sizeof(float), stream);
  k_segsum<<<(NN * DEMB + 255) / 256, 256, 0, stream>>>(h, batch, h2d, NN, DEMB);
  k_div<<<(NG * DEMB + 255) / 256, 256, 0, stream>>>(h2d, counts, NG, DEMB);

  // ---- SchNet ----
  k_rbf<<<(NE3 * NRBF + 255) / 256, 256, 0, stream>>>(ei3, pos, rbf, C3);
  k_hsinit<<<(NN * DSCH + 255) / 256, 256, 0, stream>>>(z, sch_emb, hs);
  for (int l = 0; l < 6; ++l) {
    run_gemm(stream, hs, nullptr, s_lin1W + (size_t)l * 16384, nullptr, nullptr, nullptr, nullptr,
             x1, NN, 128, 128, 128, 0);
    hipMemsetAsync(agg3, 0, (size_t)NN * DSCH * sizeof(float), stream);
    k_filter_conv<<<NE3 / 32, 256, 0, stream>>>(rbf, C3, x1, ei3, ei3 + NE3,
                                                s_mW1 + (size_t)l * 6400, s_mb1 + l * 128,
                                                s_mW2 + (size_t)l * 16384, s_mb2 + l * 128, agg3);
    run_gemm(stream, agg3, nullptr, s_lin2W + (size_t)l * 16384, s_lin2b + l * 128, nullptr,
             nullptr, nullptr, sx2, NN, 128, 128, 128, 2);
    run_gemm(stream, sx2, nullptr, s_linW + (size_t)l * 16384, s_linb + l * 128, nullptr, nullptr,
             hs, hs, NN, 128, 128, 128, 0);
  }
  hipMemsetAsync(h3d, 0, (size_t)NG * DSCH * sizeof(float), stream);
  k_segsum<<<(NN * DSCH + 255) / 256, 256, 0, stream>>>(hs, batch, h3d, NN, DSCH);
  k_div<<<(NG * DSCH + 255) / 256, 256, 0, stream>>>(h3d, counts, NG, DSCH);

  // ---- fusion + classifier ----
  run_gemm(stream, h2d, nullptr, p2W, p2b, nullptr, nullptr, nullptr, hcat, NG, 300, 300, 600, 0);
  run_gemm(stream, h3d, nullptr, p3W, p3b, nullptr, nullptr, nullptr, hcat + 300, NG, 300, 128, 600,
           0);
  run_gemm(stream, hcat, nullptr, gW1, gb1, nullptr, nullptr, nullptr, gh, NG, 128, 600, 128, 1);
  k_gate<<<2, 256, 0, stream>>>(gh, gW2, gb2, gbuf);
  k_hf<<<(NG * DEMB + 255) / 256, 256, 0, stream>>>(gbuf, hcat, hf);
  run_gemm(stream, hf, nullptr, cW1, cb1, nullptr, nullptr, nullptr, c1, NG, 150, 300, 150, 1);
  run_gemm(stream, c1, nullptr, cW2, cb2, nullptr, nullptr, nullptr, (float*)d_out, NG, 12, 150, 12,
           0);
}